// Round 2
// baseline (352.613 us; speedup 1.0000x reference)
//
#include <hip/hip_runtime.h>

namespace {

constexpr int NS = 256;      // samples
constexpr int MP = 128;      // patches
constexpr int TSTEPS = 200;  // timesteps
constexpr int BLK = 256;     // threads per block (4 waves: setup only)

__device__ __forceinline__ float4 ldg4(const float* p) {
  return *reinterpret_cast<const float4*>(p);
}
__device__ __forceinline__ float clamp01(float v) {
  return fminf(fmaxf(v, 0.0f), 1.0f);
}

__global__ __launch_bounds__(BLK, 1)
void sir_meta_kernel(const float* __restrict__ Rg,
                     const float* __restrict__ Tg,
                     const float* __restrict__ rho0g,
                     const float* __restrict__ betag,
                     float* __restrict__ outg)
{
  __shared__ __align__(16) float rs[MP];           // 1/rowsum
  __shared__ __align__(16) float binv[MP];         // beta/neff
  __shared__ __align__(16) float scr[BLK];
  __shared__ __align__(16) float xbuf[MP];         // rho[:,0] (single buffer: 1-wave lockstep)
  __shared__ __align__(16) float bcf[MP * MP];     // binv-scaled R, 64 KB, float4-linear
  __shared__ __align__(16) float gbuf[MP * 132];   // G rows, stride 132 (16B-aligned, bank-spread)

  const int tid = threadIdx.x;
  const int n = blockIdx.x;
  const float* __restrict__ Rn = Rg + (size_t)n * MP * MP;

  // ---- S1: row sums (coalesced, shfl-reduced) -> rs = 1/rowsum ----
  {
    const int wave = tid >> 6;
    const int lane = tid & 63;
    const int half = lane >> 5;
    const int l32 = lane & 31;
    for (int it = 0; it < 16; ++it) {
      const int row = wave * 32 + it * 2 + half;
      float4 v = ldg4(Rn + row * MP + l32 * 4);
      float s = (v.x + v.y) + (v.z + v.w);
      s += __shfl_xor(s, 1);
      s += __shfl_xor(s, 2);
      s += __shfl_xor(s, 4);
      s += __shfl_xor(s, 8);
      s += __shfl_xor(s, 16);
      if (l32 == 0) rs[row] = 1.0f / s;
    }
  }
  __syncthreads();

  // ---- S2: neff[k] = sum_i Rraw[i][k]*rs[i] -> binv = beta/neff ----
  {
    const int k = tid & 127;
    const int h = tid >> 7;
    float acc = 0.0f;
    #pragma unroll 8
    for (int i = 0; i < 64; ++i) {
      const int ig = h * 64 + i;
      acc = fmaf(Rn[ig * MP + k], rs[ig], acc);
    }
    scr[tid] = acc;
  }
  __syncthreads();
  if (tid < 128) binv[tid] = betag[n] / (scr[tid] + scr[tid + 128]);
  __syncthreads();

  // ---- S3a: own raw row -> registers (overlaps staging loads) ----
  const int j = tid >> 1;           // owned G row
  const int ihb = (tid & 1) * 64;   // column half
  float4 a4[32];
  #pragma unroll
  for (int q = 0; q < 32; ++q) a4[q] = ldg4(Rn + j * MP + q * 4);

  // ---- S3b: stage binv-scaled R into LDS (linear float4: conflict-free) ----
  {
    float4* bcf4 = reinterpret_cast<float4*>(bcf);
    #pragma unroll
    for (int u = 0; u < 16; ++u) {
      const int fi = u * BLK + tid;        // float4 index 0..4095, coalesced
      const int qq = fi & 31;              // 32 float4 per row
      float4 rv = ldg4(Rn + fi * 4);       // row-major linear == fi*4 floats
      float4 bv = *reinterpret_cast<const float4*>(&binv[qq * 4]);
      bcf4[fi] = make_float4(rv.x * bv.x, rv.y * bv.y, rv.z * bv.z, rv.w * bv.w);
    }
  }
  __syncthreads();

  // ---- S3c: G[j][ihb+i2] = rs[j]*rs[gi] * <Rraw[j,:], binv.*Rraw[gi,:]> ----
  {
    const float4* bcf4 = reinterpret_cast<const float4*>(bcf);
    const float rj = rs[j];
    #pragma unroll 2
    for (int i2 = 0; i2 < 64; ++i2) {
      const int gi = ihb + i2;
      const float4* src = &bcf4[gi * 32];   // broadcast reads (2 addrs/wave: free)
      float c0 = 0.f, c1 = 0.f, c2 = 0.f, c3 = 0.f;
      #pragma unroll
      for (int q = 0; q < 32; ++q) {
        float4 b = src[q];
        c0 = fmaf(a4[q].x, b.x, c0);
        c1 = fmaf(a4[q].y, b.y, c1);
        c2 = fmaf(a4[q].z, b.z, c2);
        c3 = fmaf(a4[q].w, b.w, c3);
      }
      gbuf[j * 132 + gi] = ((c0 + c1) + (c2 + c3)) * rj * rs[gi];
    }
  }
  __syncthreads();

  // ---- waves 1..3 retire; wave 0 runs the whole recurrence barrier-free ----
  if (tid >= 64) return;
  const int l = tid;

  float4 wA[32], wB[32];                    // G rows l and l+64: 256 VGPRs
  #pragma unroll
  for (int q = 0; q < 32; ++q)
    wA[q] = *reinterpret_cast<const float4*>(&gbuf[l * 132 + q * 4]);
  #pragma unroll
  for (int q = 0; q < 32; ++q)
    wB[q] = *reinterpret_cast<const float4*>(&gbuf[(l + 64) * 132 + q * 4]);

  const float* Tn = Tg + n * 9;
  const float T00 = Tn[0], T01 = Tn[1], T02 = Tn[2];
  const float T10 = Tn[3], T11 = Tn[4], T12 = Tn[5];
  const float T20 = Tn[6], T21 = Tn[7], T22 = Tn[8];

  const float* rA = rho0g + ((size_t)n * MP + l) * 3;
  const float* rB = rho0g + ((size_t)n * MP + l + 64) * 3;
  float a0 = rA[0], a1 = rA[1], a2 = rA[2];
  float b0 = rB[0], b1 = rB[1], b2 = rB[2];

  xbuf[l] = a0;
  xbuf[l + 64] = b0;
  asm volatile("s_waitcnt lgkmcnt(0)" ::: "memory");

  const float4* xb4 = reinterpret_cast<const float4*>(xbuf);
  float4* out4 = reinterpret_cast<float4*>(outg) + (size_t)n * TSTEPS * MP;

  for (int s = 0; s < TSTEPS; ++s) {
    // matvec: rows l and l+64 fully in-lane; x broadcast from LDS
    float pA0 = 0.f, pA1 = 0.f, pA2 = 0.f, pA3 = 0.f;
    float pB0 = 0.f, pB1 = 0.f, pB2 = 0.f, pB3 = 0.f;
    #pragma unroll
    for (int q = 0; q < 32; ++q) {
      float4 x = xb4[q];
      pA0 = fmaf(wA[q].x, x.x, pA0);
      pA1 = fmaf(wA[q].y, x.y, pA1);
      pA2 = fmaf(wA[q].z, x.z, pA2);
      pA3 = fmaf(wA[q].w, x.w, pA3);
      pB0 = fmaf(wB[q].x, x.x, pB0);
      pB1 = fmaf(wB[q].y, x.y, pB1);
      pB2 = fmaf(wB[q].z, x.z, pB2);
      pB3 = fmaf(wB[q].w, x.w, pB3);
    }
    const float rpA = (pA0 + pA1) + (pA2 + pA3);
    const float rpB = (pB0 + pB1) + (pB2 + pB3);

    // emit pre-update state (coalesced 1KB stores, never waited on)
    const float SA = 1.0f - ((a0 + a1) + a2);
    const float SB = 1.0f - ((b0 + b1) + b2);
    out4[s * MP + l]      = make_float4(SA, a0, a1, a2);
    out4[s * MP + l + 64] = make_float4(SB, b0, b1, b2);

    // state update + clip
    const float niA = SA * rpA;
    const float niB = SB * rpB;
    const float na0 = clamp01(fmaf(a0, T00, fmaf(a1, T10, fmaf(a2, T20, niA))));
    const float na1 = clamp01(fmaf(a0, T01, fmaf(a1, T11, a2 * T21)));
    const float na2 = clamp01(fmaf(a0, T02, fmaf(a1, T12, a2 * T22)));
    const float nb0 = clamp01(fmaf(b0, T00, fmaf(b1, T10, fmaf(b2, T20, niB))));
    const float nb1 = clamp01(fmaf(b0, T01, fmaf(b1, T11, b2 * T21)));
    const float nb2 = clamp01(fmaf(b0, T02, fmaf(b1, T12, b2 * T22)));
    a0 = na0; a1 = na1; a2 = na2;
    b0 = nb0; b1 = nb1; b2 = nb2;

    // same-wave exchange: writes issue after all reads (lockstep), so a
    // single buffer is race-free; lgkmcnt(0) makes them visible to next reads
    xbuf[l] = a0;
    xbuf[l + 64] = b0;
    asm volatile("s_waitcnt lgkmcnt(0)" ::: "memory");
  }
}

} // namespace

extern "C" void kernel_launch(void* const* d_in, const int* in_sizes, int n_in,
                              void* d_out, int out_size, void* d_ws, size_t ws_size,
                              hipStream_t stream)
{
  const float* Rg    = (const float*)d_in[0];
  const float* Tg    = (const float*)d_in[1];
  const float* rho0g = (const float*)d_in[2];
  const float* betag = (const float*)d_in[3];
  float* outg = (float*)d_out;
  sir_meta_kernel<<<NS, BLK, 0, stream>>>(Rg, Tg, rho0g, betag, outg);
}

// Round 3
// 169.925 us; speedup vs baseline: 2.0751x; 2.0751x over previous
//
#include <hip/hip_runtime.h>

namespace {

constexpr int NS = 256;      // samples
constexpr int MP = 128;      // patches
constexpr int TSTEPS = 200;  // timesteps
constexpr int BLK = 256;     // 4 waves

__device__ __forceinline__ float4 ldg4(const float* p) {
  return *reinterpret_cast<const float4*>(p);
}
__device__ __forceinline__ float clamp01(float v) {
  return fminf(fmaxf(v, 0.0f), 1.0f);
}
// Barrier that does NOT drain vmcnt: LDS visibility only. Keeps output
// stores fire-and-forget across steps.
__device__ __forceinline__ void step_barrier() {
  asm volatile("s_waitcnt lgkmcnt(0)" ::: "memory");
  __builtin_amdgcn_s_barrier();
  asm volatile("" ::: "memory");
}

__global__ __launch_bounds__(BLK, 1)
void sir_meta_kernel(const float* __restrict__ Rg,
                     const float* __restrict__ Tg,
                     const float* __restrict__ rho0g,
                     const float* __restrict__ betag,
                     float* __restrict__ outg)
{
  __shared__ __align__(16) float rs[MP];        // 1/rowsum
  __shared__ __align__(16) float binv[MP];      // beta/neff
  __shared__ __align__(16) float scr[BLK];
  __shared__ __align__(16) float xb[2][MP];     // rho[:,0] double buffer
  __shared__ __align__(16) float bcf[MP * MP];  // binv-scaled R (64 KB)

  const int tid = threadIdx.x;
  const int n = blockIdx.x;
  const float* __restrict__ Rn = Rg + (size_t)n * MP * MP;

  // ---- S1: row sums -> rs = 1/rowsum ----
  {
    const int wave = tid >> 6;
    const int lane = tid & 63;
    const int half = lane >> 5;
    const int l32 = lane & 31;
    for (int it = 0; it < 16; ++it) {
      const int row = wave * 32 + it * 2 + half;
      float4 v = ldg4(Rn + row * MP + l32 * 4);
      float s = (v.x + v.y) + (v.z + v.w);
      s += __shfl_xor(s, 1);
      s += __shfl_xor(s, 2);
      s += __shfl_xor(s, 4);
      s += __shfl_xor(s, 8);
      s += __shfl_xor(s, 16);
      if (l32 == 0) rs[row] = 1.0f / s;
    }
  }
  __syncthreads();

  // ---- S2: neff[k] = sum_i Rraw[i][k]*rs[i] -> binv = beta/neff ----
  {
    const int k = tid & 127;
    const int h = tid >> 7;
    float acc = 0.0f;
    #pragma unroll 8
    for (int i = 0; i < 64; ++i) {
      const int ig = h * 64 + i;
      acc = fmaf(Rn[ig * MP + k], rs[ig], acc);
    }
    scr[tid] = acc;
  }
  __syncthreads();
  if (tid < 128) binv[tid] = betag[n] / (scr[tid] + scr[tid + 128]);
  __syncthreads();

  // ---- S3a: own raw row -> registers ----
  const int j = tid >> 1;           // owned G row (2 lanes per row)
  const int ihb = (tid & 1) * 64;   // column half
  float4 a4[32];
  #pragma unroll
  for (int q = 0; q < 32; ++q) a4[q] = ldg4(Rn + j * MP + q * 4);

  // ---- S3b: stage binv-scaled R into LDS (linear float4, conflict-free) ----
  {
    float4* bcf4 = reinterpret_cast<float4*>(bcf);
    #pragma unroll
    for (int u = 0; u < 16; ++u) {
      const int fi = u * BLK + tid;
      const int qq = fi & 31;
      float4 rv = ldg4(Rn + fi * 4);
      float4 bv = *reinterpret_cast<const float4*>(&binv[qq * 4]);
      bcf4[fi] = make_float4(rv.x * bv.x, rv.y * bv.y, rv.z * bv.z, rv.w * bv.w);
    }
  }
  __syncthreads();

  // ---- S3c: w[i2] = rs[j]*rs[gi] * <Rraw[j,:], binv.*Rraw[gi,:]> ----
  float w[64];
  {
    const float4* bcf4 = reinterpret_cast<const float4*>(bcf);
    const float rj = rs[j];
    #pragma unroll 2
    for (int i2 = 0; i2 < 64; ++i2) {
      const int gi = ihb + i2;
      const float4* src = &bcf4[gi * 32];   // 2 addrs/wave: free broadcast
      float c0 = 0.f, c1 = 0.f, c2 = 0.f, c3 = 0.f;
      #pragma unroll
      for (int q = 0; q < 32; ++q) {
        float4 b = src[q];
        c0 = fmaf(a4[q].x, b.x, c0);
        c1 = fmaf(a4[q].y, b.y, c1);
        c2 = fmaf(a4[q].z, b.z, c2);
        c3 = fmaf(a4[q].w, b.w, c3);
      }
      w[i2] = ((c0 + c1) + (c2 + c3)) * rj * rs[gi];
    }
  }

  // ---- S4: init state (both lanes of a pair hold row j's rho) ----
  float r0 = rho0g[((size_t)n * MP + j) * 3 + 0];
  float r1 = rho0g[((size_t)n * MP + j) * 3 + 1];
  float r2 = rho0g[((size_t)n * MP + j) * 3 + 2];
  const float* Tn = Tg + n * 9;
  const float T00 = Tn[0], T01 = Tn[1], T02 = Tn[2];
  const float T10 = Tn[3], T11 = Tn[4], T12 = Tn[5];
  const float T20 = Tn[6], T21 = Tn[7], T22 = Tn[8];
  if ((tid & 1) == 0) xb[0][j] = r0;
  __syncthreads();

  float4* out4 = reinterpret_cast<float4*>(outg) + (size_t)n * TSTEPS * MP;

  for (int s = 0; s < TSTEPS; ++s) {
    // emit pre-update state early (coalesced 512B/wave, never waited on)
    const float S = 1.0f - ((r0 + r1) + r2);
    if (tid & 1) out4[s * MP + j] = make_float4(S, r0, r1, r2);

    // half-row matvec from registers; x broadcast from LDS (2 addrs/instr)
    const float4* xv = reinterpret_cast<const float4*>(&xb[s & 1][ihb]);
    float p0 = 0.f, p1 = 0.f, p2 = 0.f, p3 = 0.f;
    #pragma unroll
    for (int q = 0; q < 16; ++q) {
      float4 x = xv[q];
      p0 = fmaf(w[4*q+0], x.x, p0);
      p1 = fmaf(w[4*q+1], x.y, p1);
      p2 = fmaf(w[4*q+2], x.z, p2);
      p3 = fmaf(w[4*q+3], x.w, p3);
    }
    float acc = (p0 + p1) + (p2 + p3);
    const float rp = acc + __shfl_xor(acc, 1);  // combine column halves

    // state update + clip
    const float ni = S * rp;
    const float n0 = clamp01(fmaf(r0, T00, fmaf(r1, T10, fmaf(r2, T20, ni))));
    const float n1 = clamp01(fmaf(r0, T01, fmaf(r1, T11, r2 * T21)));
    const float n2 = clamp01(fmaf(r0, T02, fmaf(r1, T12, r2 * T22)));
    r0 = n0; r1 = n1; r2 = n2;
    if ((tid & 1) == 0) xb[(s & 1) ^ 1][j] = n0;

    // LDS-only barrier: x writes visible; stores stay in flight
    step_barrier();
  }
}

} // namespace

extern "C" void kernel_launch(void* const* d_in, const int* in_sizes, int n_in,
                              void* d_out, int out_size, void* d_ws, size_t ws_size,
                              hipStream_t stream)
{
  const float* Rg    = (const float*)d_in[0];
  const float* Tg    = (const float*)d_in[1];
  const float* rho0g = (const float*)d_in[2];
  const float* betag = (const float*)d_in[3];
  float* outg = (float*)d_out;
  sir_meta_kernel<<<NS, BLK, 0, stream>>>(Rg, Tg, rho0g, betag, outg);
}

// Round 4
// 161.896 us; speedup vs baseline: 2.1780x; 1.0496x over previous
//
#include <hip/hip_runtime.h>

namespace {

constexpr int NS = 256;      // samples
constexpr int MP = 128;      // patches
constexpr int TSTEPS = 200;  // timesteps
constexpr int BLK = 256;     // 4 waves

__device__ __forceinline__ float4 ldg4(const float* p) {
  return *reinterpret_cast<const float4*>(p);
}
__device__ __forceinline__ float clamp01(float v) {
  return fminf(fmaxf(v, 0.0f), 1.0f);
}
// Barrier that does NOT drain vmcnt: LDS visibility only. Keeps output
// stores fire-and-forget across steps.
__device__ __forceinline__ void step_barrier() {
  asm volatile("s_waitcnt lgkmcnt(0)" ::: "memory");
  __builtin_amdgcn_s_barrier();
  asm volatile("" ::: "memory");
}

// bcf layout: row stride 33 float4 (132 floats); rows >=64 shifted +1 float4
// so the S3c pair's two broadcast addresses differ by 4 banks (not 0).
__device__ __forceinline__ int bcf_idx4(int r, int c) {
  return r * 33 + (r >> 6) + c;
}

__global__ __launch_bounds__(BLK, 1)
void sir_meta_kernel(const float* __restrict__ Rg,
                     const float* __restrict__ Tg,
                     const float* __restrict__ rho0g,
                     const float* __restrict__ betag,
                     float* __restrict__ outg)
{
  __shared__ __align__(16) float rs[MP];        // 1/rowsum
  __shared__ __align__(16) float binv[MP];      // beta/neff
  __shared__ __align__(16) float scr[BLK];
  // x double buffer: half-0 at [0..63], half-1 at [72..135] (+8-float shift
  // => the loop's two broadcast reads hit disjoint bank groups)
  __shared__ __align__(16) float xb[2][136];
  __shared__ __align__(16) float bcf[4224 * 4]; // binv-scaled R, shifted layout (66 KB)

  const int tid = threadIdx.x;
  const int n = blockIdx.x;
  const float* __restrict__ Rn = Rg + (size_t)n * MP * MP;

  // ---- S1: row sums -> rs = 1/rowsum ----
  {
    const int wave = tid >> 6;
    const int lane = tid & 63;
    const int half = lane >> 5;
    const int l32 = lane & 31;
    for (int it = 0; it < 16; ++it) {
      const int row = wave * 32 + it * 2 + half;
      float4 v = ldg4(Rn + row * MP + l32 * 4);
      float s = (v.x + v.y) + (v.z + v.w);
      s += __shfl_xor(s, 1);
      s += __shfl_xor(s, 2);
      s += __shfl_xor(s, 4);
      s += __shfl_xor(s, 8);
      s += __shfl_xor(s, 16);
      if (l32 == 0) rs[row] = 1.0f / s;
    }
  }
  __syncthreads();

  // ---- S2: neff[k] = sum_i Rraw[i][k]*rs[i] -> binv = beta/neff ----
  {
    const int k = tid & 127;
    const int h = tid >> 7;
    float acc = 0.0f;
    #pragma unroll 8
    for (int i = 0; i < 64; ++i) {
      const int ig = h * 64 + i;
      acc = fmaf(Rn[ig * MP + k], rs[ig], acc);
    }
    scr[tid] = acc;
  }
  __syncthreads();
  if (tid < 128) binv[tid] = betag[n] / (scr[tid] + scr[tid + 128]);
  __syncthreads();

  // ---- S3a: own raw row -> registers ----
  const int j = tid >> 1;           // owned G row (2 lanes per row)
  const int ihb = (tid & 1) * 64;   // column half
  float4 a4[32];
  #pragma unroll
  for (int q = 0; q < 32; ++q) a4[q] = ldg4(Rn + j * MP + q * 4);

  // ---- S3b: stage binv-scaled R into LDS (shifted layout) ----
  {
    float4* bcf4 = reinterpret_cast<float4*>(bcf);
    #pragma unroll
    for (int u = 0; u < 16; ++u) {
      const int fi = u * BLK + tid;        // coalesced float4 index
      const int r = fi >> 5;
      const int c = fi & 31;
      float4 rv = ldg4(Rn + fi * 4);
      float4 bv = *reinterpret_cast<const float4*>(&binv[c * 4]);
      bcf4[bcf_idx4(r, c)] =
          make_float4(rv.x * bv.x, rv.y * bv.y, rv.z * bv.z, rv.w * bv.w);
    }
  }
  __syncthreads();

  // ---- S3c: w[i2] = rs[j]*rs[gi] * <Rraw[j,:], binv.*Rraw[gi,:]> ----
  float w[64];
  {
    const float4* bcf4 = reinterpret_cast<const float4*>(bcf);
    const float rj = rs[j];
    const int sh = tid & 1;               // row-half shift (uniform VGPR math)
    #pragma unroll 2
    for (int i2 = 0; i2 < 64; ++i2) {
      const int gi = ihb + i2;
      const float4* src = &bcf4[gi * 33 + sh];  // 2 addrs/wave, disjoint banks
      float c0 = 0.f, c1 = 0.f, c2 = 0.f, c3 = 0.f;
      #pragma unroll
      for (int q = 0; q < 32; ++q) {
        float4 b = src[q];
        c0 = fmaf(a4[q].x, b.x, c0);
        c1 = fmaf(a4[q].y, b.y, c1);
        c2 = fmaf(a4[q].z, b.z, c2);
        c3 = fmaf(a4[q].w, b.w, c3);
      }
      w[i2] = ((c0 + c1) + (c2 + c3)) * rj * rs[gi];
    }
  }

  // ---- S4: init state (both lanes of a pair hold row j's rho) ----
  float r0 = rho0g[((size_t)n * MP + j) * 3 + 0];
  float r1 = rho0g[((size_t)n * MP + j) * 3 + 1];
  float r2 = rho0g[((size_t)n * MP + j) * 3 + 2];
  const float* Tn = Tg + n * 9;
  const float T00 = Tn[0], T01 = Tn[1], T02 = Tn[2];
  const float T10 = Tn[3], T11 = Tn[4], T12 = Tn[5];
  const float T20 = Tn[6], T21 = Tn[7], T22 = Tn[8];
  const int xsl = j + ((j >> 6) << 3);   // shifted x slot for row j
  const int xbase = ihb + ((ihb >> 6) << 3);  // 0 or 72 floats (16B-aligned)
  if ((tid & 1) == 0) xb[0][xsl] = r0;
  __syncthreads();

  float4* out4 = reinterpret_cast<float4*>(outg) + (size_t)n * TSTEPS * MP;

  for (int s = 0; s < TSTEPS; ++s) {
    // emit pre-update state early (coalesced, never waited on)
    const float S = 1.0f - ((r0 + r1) + r2);
    if (tid & 1) out4[s * MP + j] = make_float4(S, r0, r1, r2);

    // half-row matvec from registers; x broadcast from LDS
    // (2 addresses per instr, disjoint bank groups -> conflict-free)
    const float4* xv = reinterpret_cast<const float4*>(&xb[s & 1][xbase]);
    float p0 = 0.f, p1 = 0.f, p2 = 0.f, p3 = 0.f;
    #pragma unroll
    for (int q = 0; q < 16; ++q) {
      float4 x = xv[q];
      p0 = fmaf(w[4*q+0], x.x, p0);
      p1 = fmaf(w[4*q+1], x.y, p1);
      p2 = fmaf(w[4*q+2], x.z, p2);
      p3 = fmaf(w[4*q+3], x.w, p3);
    }
    float acc = (p0 + p1) + (p2 + p3);
    const float rp = acc + __shfl_xor(acc, 1);  // combine column halves

    // state update + clip
    const float ni = S * rp;
    const float n0 = clamp01(fmaf(r0, T00, fmaf(r1, T10, fmaf(r2, T20, ni))));
    const float n1 = clamp01(fmaf(r0, T01, fmaf(r1, T11, r2 * T21)));
    const float n2 = clamp01(fmaf(r0, T02, fmaf(r1, T12, r2 * T22)));
    r0 = n0; r1 = n1; r2 = n2;
    if ((tid & 1) == 0) xb[(s & 1) ^ 1][xsl] = n0;

    // LDS-only barrier: x writes visible; stores stay in flight
    step_barrier();
  }
}

} // namespace

extern "C" void kernel_launch(void* const* d_in, const int* in_sizes, int n_in,
                              void* d_out, int out_size, void* d_ws, size_t ws_size,
                              hipStream_t stream)
{
  const float* Rg    = (const float*)d_in[0];
  const float* Tg    = (const float*)d_in[1];
  const float* rho0g = (const float*)d_in[2];
  const float* betag = (const float*)d_in[3];
  float* outg = (float*)d_out;
  sir_meta_kernel<<<NS, BLK, 0, stream>>>(Rg, Tg, rho0g, betag, outg);
}

// Round 5
// 102.648 us; speedup vs baseline: 3.4352x; 1.5772x over previous
//
#include <hip/hip_runtime.h>

namespace {

constexpr int NS = 256;      // samples
constexpr int MP = 128;      // patches
constexpr int TSTEPS = 200;  // timesteps
constexpr int BLK = 256;     // 4 waves

__device__ __forceinline__ float4 ldg4(const float* p) {
  return *reinterpret_cast<const float4*>(p);
}
__device__ __forceinline__ float clamp01(float v) {
  return fminf(fmaxf(v, 0.0f), 1.0f);
}
// LDS-visibility barrier that does NOT drain vmcnt (stores stay in flight).
__device__ __forceinline__ void step_barrier() {
  asm volatile("s_waitcnt lgkmcnt(0)" ::: "memory");
  __builtin_amdgcn_s_barrier();
  asm volatile("" ::: "memory");
}
// VALU-pipe rotate-add within each 16-lane DPP row: after ror 1,2,4,8 every
// lane holds the 16-lane sum. No LDS ops.
template <int CTRL>
__device__ __forceinline__ float dpp_radd(float x) {
  int yi = __builtin_amdgcn_update_dpp(0, __float_as_int(x), CTRL, 0xF, 0xF, true);
  return x + __int_as_float(yi);
}
// Swizzled float4 index into Q: XOR row-octet into the column-quad so
// same-column reads of rows 8 apart land on distinct bank quads.
__device__ __forceinline__ int qidx(int row, int c4) {
  return (row << 5) + (c4 ^ ((row >> 3) & 7));
}

__global__ __launch_bounds__(BLK, 1)
void sir_meta_kernel(const float* __restrict__ Rg,
                     const float* __restrict__ Tg,
                     const float* __restrict__ rho0g,
                     const float* __restrict__ betag,
                     float* __restrict__ outg)
{
  __shared__ __align__(16) float rs[MP];       // 1/rowsum
  __shared__ __align__(16) float sbin[MP];     // sqrt(beta/neff)
  __shared__ __align__(16) float scr[BLK];
  __shared__ __align__(16) float xb[2][MP];    // rho[:,0] double buffer
  __shared__ __align__(16) float qlds[MP * MP]; // Q = R*diag(sbin), swizzled (64KB)

  const int tid = threadIdx.x;
  const int n = blockIdx.x;
  const float* __restrict__ Rn = Rg + (size_t)n * MP * MP;

  // ---- S1: row sums -> rs = 1/rowsum ----
  {
    const int wave = tid >> 6;
    const int lane = tid & 63;
    const int half = lane >> 5;
    const int l32 = lane & 31;
    for (int it = 0; it < 16; ++it) {
      const int row = wave * 32 + it * 2 + half;
      float4 v = ldg4(Rn + row * MP + l32 * 4);
      float s = (v.x + v.y) + (v.z + v.w);
      s += __shfl_xor(s, 1);
      s += __shfl_xor(s, 2);
      s += __shfl_xor(s, 4);
      s += __shfl_xor(s, 8);
      s += __shfl_xor(s, 16);
      if (l32 == 0) rs[row] = 1.0f / s;
    }
  }
  __syncthreads();

  // ---- S2: neff[k] = sum_i Rraw[i][k]*rs[i] -> sbin = sqrt(beta/neff) ----
  {
    const int k = tid & 127;
    const int h = tid >> 7;
    float acc = 0.0f;
    #pragma unroll 8
    for (int i = 0; i < 64; ++i) {
      const int ig = h * 64 + i;
      acc = fmaf(Rn[ig * MP + k], rs[ig], acc);
    }
    scr[tid] = acc;
  }
  __syncthreads();
  if (tid < 128) sbin[tid] = sqrtf(betag[n] / (scr[tid] + scr[tid + 128]));
  __syncthreads();

  // ---- S3a: stage Q = Rraw * diag(sbin) into LDS, swizzled ----
  {
    float4* q4 = reinterpret_cast<float4*>(qlds);
    #pragma unroll
    for (int u = 0; u < 16; ++u) {
      const int fi = u * BLK + tid;        // coalesced float4 index
      const int r = fi >> 5, c4 = fi & 31;
      float4 rv = ldg4(Rn + fi * 4);
      float4 sv = *reinterpret_cast<const float4*>(&sbin[c4 * 4]);
      q4[qidx(r, c4)] =
          make_float4(rv.x * sv.x, rv.y * sv.y, rv.z * sv.z, rv.w * sv.w);
    }
  }
  __syncthreads();

  // Tile mapping: wave wv (0..3), group g (0..3) of 16 lanes, lane k (0..15).
  // Lane owns G rows [rbase..rbase+8) x cols [cbase..cbase+8).
  const int wv = tid >> 6;
  const int g = (tid >> 4) & 3;
  const int k = tid & 15;
  const int rbase = wv * 32 + g * 8;
  const int cbase = k * 8;

  // ---- S3b: register-tiled GEMM  acc[r][c] = <Q[rbase+r,:], Q[cbase+c,:]> ----
  float acc[64];
  #pragma unroll
  for (int i = 0; i < 64; ++i) acc[i] = 0.0f;
  {
    const float4* q4 = reinterpret_cast<const float4*>(qlds);
    for (int kk = 0; kk < 32; ++kk) {
      float4 qa[8], qb[8];
      #pragma unroll
      for (int r = 0; r < 8; ++r) qa[r] = q4[qidx(rbase + r, kk)];  // 4 addrs/wave
      #pragma unroll
      for (int c = 0; c < 8; ++c) qb[c] = q4[qidx(cbase + c, kk)];  // swizzle-spread
      #pragma unroll
      for (int r = 0; r < 8; ++r) {
        #pragma unroll
        for (int c = 0; c < 8; ++c) {
          float a = acc[r * 8 + c];
          a = fmaf(qa[r].x, qb[c].x, a);
          a = fmaf(qa[r].y, qb[c].y, a);
          a = fmaf(qa[r].z, qb[c].z, a);
          a = fmaf(qa[r].w, qb[c].w, a);
          acc[r * 8 + c] = a;
        }
      }
    }
  }
  // scale in place: G = diag(rs) * (Q Q^T) * diag(rs)
  {
    float rsr[8], rsc[8];
    #pragma unroll
    for (int r = 0; r < 8; ++r) rsr[r] = rs[rbase + r];
    #pragma unroll
    for (int c = 0; c < 8; ++c) rsc[c] = rs[cbase + c];
    #pragma unroll
    for (int r = 0; r < 8; ++r)
      #pragma unroll
      for (int c = 0; c < 8; ++c)
        acc[r * 8 + c] *= rsr[r] * rsc[c];
  }

  // ---- S4: state init. Lane updates row j = rbase + (k&7); 2x redundant. ----
  const int j = rbase + (k & 7);
  const bool writer = (k < 8);
  const float* Tn = Tg + n * 9;
  const float T00 = Tn[0], T01 = Tn[1], T02 = Tn[2];
  const float T10 = Tn[3], T11 = Tn[4], T12 = Tn[5];
  const float T20 = Tn[6], T21 = Tn[7], T22 = Tn[8];
  const float* rp0 = rho0g + ((size_t)n * MP + j) * 3;
  float r0 = rp0[0], r1 = rp0[1], r2 = rp0[2];
  if (writer) xb[0][j] = r0;
  __syncthreads();

  float4* outp = reinterpret_cast<float4*>(outg) + (size_t)n * TSTEPS * MP + j;

  for (int s = 0; s < TSTEPS; ++s) {
    // emit pre-update state (coalesced 512B/wave, fire-and-forget)
    const float S = 1.0f - ((r0 + r1) + r2);
    if (writer) *outp = make_float4(S, r0, r1, r2);
    outp += MP;

    // 8 x-floats per lane (2 ds_read_b128 per lane; 8 KB/CU/step total)
    const float* xc = xb[s & 1];
    const float4 xA = *reinterpret_cast<const float4*>(&xc[cbase]);
    const float4 xB = *reinterpret_cast<const float4*>(&xc[cbase + 4]);

    // 8x8 tile matvec partials
    float p[8];
    #pragma unroll
    for (int r = 0; r < 8; ++r) {
      float a = fmaf(acc[r * 8 + 0], xA.x, acc[r * 8 + 1] * xA.y);
      a = fmaf(acc[r * 8 + 2], xA.z, a);
      a = fmaf(acc[r * 8 + 3], xA.w, a);
      a = fmaf(acc[r * 8 + 4], xB.x, a);
      a = fmaf(acc[r * 8 + 5], xB.y, a);
      a = fmaf(acc[r * 8 + 6], xB.z, a);
      a = fmaf(acc[r * 8 + 7], xB.w, a);
      p[r] = a;
    }
    // 16-lane rotate-add reduce on the VALU pipe (no LDS)
    #pragma unroll
    for (int r = 0; r < 8; ++r) {
      p[r] = dpp_radd<0x121>(p[r]);  // row_ror:1
      p[r] = dpp_radd<0x122>(p[r]);  // row_ror:2
      p[r] = dpp_radd<0x124>(p[r]);  // row_ror:4
      p[r] = dpp_radd<0x128>(p[r]);  // row_ror:8
    }
    // select this lane's row sum (static regs + cndmask tree, no dyn index)
    const float t0 = (k & 1) ? p[1] : p[0];
    const float t1 = (k & 1) ? p[3] : p[2];
    const float t2 = (k & 1) ? p[5] : p[4];
    const float t3 = (k & 1) ? p[7] : p[6];
    const float u0 = (k & 2) ? t1 : t0;
    const float u1 = (k & 2) ? t3 : t2;
    const float rp = (k & 4) ? u1 : u0;

    // state update + clip
    const float ni = S * rp;
    const float n0 = clamp01(fmaf(r0, T00, fmaf(r1, T10, fmaf(r2, T20, ni))));
    const float n1 = clamp01(fmaf(r0, T01, fmaf(r1, T11, r2 * T21)));
    const float n2 = clamp01(fmaf(r0, T02, fmaf(r1, T12, r2 * T22)));
    r0 = n0; r1 = n1; r2 = n2;
    if (writer) xb[(s & 1) ^ 1][j] = n0;

    step_barrier();
  }
}

} // namespace

extern "C" void kernel_launch(void* const* d_in, const int* in_sizes, int n_in,
                              void* d_out, int out_size, void* d_ws, size_t ws_size,
                              hipStream_t stream)
{
  const float* Rg    = (const float*)d_in[0];
  const float* Tg    = (const float*)d_in[1];
  const float* rho0g = (const float*)d_in[2];
  const float* betag = (const float*)d_in[3];
  float* outg = (float*)d_out;
  sir_meta_kernel<<<NS, BLK, 0, stream>>>(Rg, Tg, rho0g, betag, outg);
}

// Round 6
// 90.143 us; speedup vs baseline: 3.9117x; 1.1387x over previous
//
#include <hip/hip_runtime.h>

namespace {

constexpr int NS = 256;      // samples
constexpr int MP = 128;      // patches
constexpr int TSTEPS = 200;  // timesteps
constexpr int BLK = 512;     // 8 waves -> 2 waves/SIMD (latency overlap)

__device__ __forceinline__ float4 ldg4(const float* p) {
  return *reinterpret_cast<const float4*>(p);
}
__device__ __forceinline__ float clamp01(float v) {
  return fminf(fmaxf(v, 0.0f), 1.0f);
}
// LDS-visibility barrier that does NOT drain vmcnt (stores stay in flight).
__device__ __forceinline__ void step_barrier() {
  asm volatile("s_waitcnt lgkmcnt(0)" ::: "memory");
  __builtin_amdgcn_s_barrier();
  asm volatile("" ::: "memory");
}
// VALU-pipe rotate-add within each 16-lane DPP row.
template <int CTRL>
__device__ __forceinline__ float dpp_radd(float x) {
  int yi = __builtin_amdgcn_update_dpp(0, __float_as_int(x), CTRL, 0xF, 0xF, true);
  return x + __int_as_float(yi);
}
// Swizzled float4 index into Q: XOR row-octet into column-quad.
__device__ __forceinline__ int qidx(int row, int c4) {
  return (row << 5) + (c4 ^ ((row >> 3) & 7));
}

__global__ __launch_bounds__(BLK, 2)
void sir_meta_kernel(const float* __restrict__ Rg,
                     const float* __restrict__ Tg,
                     const float* __restrict__ rho0g,
                     const float* __restrict__ betag,
                     float* __restrict__ outg)
{
  __shared__ __align__(16) float rs[MP];        // 1/rowsum
  __shared__ __align__(16) float sbin[MP];      // sqrt(beta/neff)
  __shared__ __align__(16) float scr[BLK];
  __shared__ __align__(16) float xb[2][MP];     // rho[:,0] double buffer
  __shared__ __align__(16) float qlds[MP * MP]; // Q = R*diag(sbin), swizzled

  const int tid = threadIdx.x;
  const int n = blockIdx.x;
  const float* __restrict__ Rn = Rg + (size_t)n * MP * MP;

  // ---- S1: row sums -> rs = 1/rowsum (8 waves x 16 rows) ----
  {
    const int wave = tid >> 6;
    const int lane = tid & 63;
    const int half = lane >> 5;
    const int l32 = lane & 31;
    for (int it = 0; it < 8; ++it) {
      const int row = wave * 16 + it * 2 + half;
      float4 v = ldg4(Rn + row * MP + l32 * 4);
      float s = (v.x + v.y) + (v.z + v.w);
      s += __shfl_xor(s, 1);
      s += __shfl_xor(s, 2);
      s += __shfl_xor(s, 4);
      s += __shfl_xor(s, 8);
      s += __shfl_xor(s, 16);
      if (l32 == 0) rs[row] = 1.0f / s;
    }
  }
  __syncthreads();

  // ---- S2: neff[c] = sum_i Rraw[i][c]*rs[i] -> sbin = sqrt(beta/neff) ----
  {
    const int c = tid & 127;
    const int h = tid >> 7;           // 4 slices of 32 rows
    float a = 0.0f;
    #pragma unroll 8
    for (int i = 0; i < 32; ++i) {
      const int ig = h * 32 + i;
      a = fmaf(Rn[ig * MP + c], rs[ig], a);
    }
    scr[tid] = a;
  }
  __syncthreads();
  if (tid < 128)
    sbin[tid] = sqrtf(betag[n] /
        (((scr[tid] + scr[tid + 128]) + (scr[tid + 256] + scr[tid + 384]))));
  __syncthreads();

  // ---- S3a: stage Q = Rraw * diag(sbin) into LDS, swizzled ----
  {
    float4* q4 = reinterpret_cast<float4*>(qlds);
    #pragma unroll
    for (int u = 0; u < 8; ++u) {
      const int fi = u * BLK + tid;       // coalesced float4 index
      const int r = fi >> 5, c4 = fi & 31;
      float4 rv = ldg4(Rn + fi * 4);
      float4 sv = *reinterpret_cast<const float4*>(&sbin[c4 * 4]);
      q4[qidx(r, c4)] =
          make_float4(rv.x * sv.x, rv.y * sv.y, rv.z * sv.z, rv.w * sv.w);
    }
  }
  __syncthreads();

  // Tile mapping: wave wv (0..7), group g (0..3) of 16 lanes, lane k (0..15).
  // Lane owns G rows [rbase..rbase+4) x cols [cbase..cbase+8).
  const int wv = tid >> 6;
  const int g = (tid >> 4) & 3;
  const int k = tid & 15;
  const int rbase = wv * 16 + g * 4;
  const int cbase = k * 8;

  // ---- S3b: register-tiled GEMM  acc[r][c] = <Q[rbase+r,:], Q[cbase+c,:]> ----
  float acc[32];
  #pragma unroll
  for (int i = 0; i < 32; ++i) acc[i] = 0.0f;
  {
    const float4* q4 = reinterpret_cast<const float4*>(qlds);
    for (int kk = 0; kk < 32; ++kk) {
      float4 qa[4], qb[8];
      #pragma unroll
      for (int r = 0; r < 4; ++r) qa[r] = q4[qidx(rbase + r, kk)];
      #pragma unroll
      for (int c = 0; c < 8; ++c) qb[c] = q4[qidx(cbase + c, kk)];
      #pragma unroll
      for (int r = 0; r < 4; ++r) {
        #pragma unroll
        for (int c = 0; c < 8; ++c) {
          float a = acc[r * 8 + c];
          a = fmaf(qa[r].x, qb[c].x, a);
          a = fmaf(qa[r].y, qb[c].y, a);
          a = fmaf(qa[r].z, qb[c].z, a);
          a = fmaf(qa[r].w, qb[c].w, a);
          acc[r * 8 + c] = a;
        }
      }
    }
  }
  // scale: G = diag(rs) * (Q Q^T) * diag(rs)
  {
    float rsr[4], rsc[8];
    #pragma unroll
    for (int r = 0; r < 4; ++r) rsr[r] = rs[rbase + r];
    #pragma unroll
    for (int c = 0; c < 8; ++c) rsc[c] = rs[cbase + c];
    #pragma unroll
    for (int r = 0; r < 4; ++r)
      #pragma unroll
      for (int c = 0; c < 8; ++c)
        acc[r * 8 + c] *= rsr[r] * rsc[c];
  }

  // ---- S4: state init. Lane updates row j = rbase + (k&3); 4x redundant. ----
  const int j = rbase + (k & 3);
  const bool writer = (k < 4);
  const float* Tn = Tg + n * 9;
  const float T00 = Tn[0], T01 = Tn[1], T02 = Tn[2];
  const float T10 = Tn[3], T11 = Tn[4], T12 = Tn[5];
  const float T20 = Tn[6], T21 = Tn[7], T22 = Tn[8];
  const float* rp0 = rho0g + ((size_t)n * MP + j) * 3;
  float r0 = rp0[0], r1 = rp0[1], r2 = rp0[2];
  if (writer) xb[0][j] = r0;
  __syncthreads();

  float4* outp = reinterpret_cast<float4*>(outg) + (size_t)n * TSTEPS * MP + j;

  for (int s = 0; s < TSTEPS; ++s) {
    // emit pre-update state (coalesced, fire-and-forget)
    const float S = 1.0f - ((r0 + r1) + r2);
    if (writer) *outp = make_float4(S, r0, r1, r2);
    outp += MP;

    // 8 x-floats per lane
    const float* xc = xb[s & 1];
    const float4 xA = *reinterpret_cast<const float4*>(&xc[cbase]);
    const float4 xB = *reinterpret_cast<const float4*>(&xc[cbase + 4]);

    // 4x8 tile matvec partials
    float p[4];
    #pragma unroll
    for (int r = 0; r < 4; ++r) {
      float a = fmaf(acc[r * 8 + 0], xA.x, acc[r * 8 + 1] * xA.y);
      a = fmaf(acc[r * 8 + 2], xA.z, a);
      a = fmaf(acc[r * 8 + 3], xA.w, a);
      a = fmaf(acc[r * 8 + 4], xB.x, a);
      a = fmaf(acc[r * 8 + 5], xB.y, a);
      a = fmaf(acc[r * 8 + 6], xB.z, a);
      a = fmaf(acc[r * 8 + 7], xB.w, a);
      p[r] = a;
    }
    // 16-lane rotate-add reduce on the VALU pipe
    #pragma unroll
    for (int r = 0; r < 4; ++r) {
      p[r] = dpp_radd<0x121>(p[r]);  // row_ror:1
      p[r] = dpp_radd<0x122>(p[r]);  // row_ror:2
      p[r] = dpp_radd<0x124>(p[r]);  // row_ror:4
      p[r] = dpp_radd<0x128>(p[r]);  // row_ror:8
    }
    // select this lane's row (static indices only)
    const float t0 = (k & 1) ? p[1] : p[0];
    const float t1 = (k & 1) ? p[3] : p[2];
    const float rp = (k & 2) ? t1 : t0;

    // state update + clip
    const float ni = S * rp;
    const float n0 = clamp01(fmaf(r0, T00, fmaf(r1, T10, fmaf(r2, T20, ni))));
    const float n1 = clamp01(fmaf(r0, T01, fmaf(r1, T11, r2 * T21)));
    const float n2 = clamp01(fmaf(r0, T02, fmaf(r1, T12, r2 * T22)));
    r0 = n0; r1 = n1; r2 = n2;
    if (writer) xb[(s & 1) ^ 1][j] = n0;

    step_barrier();
  }
}

} // namespace

extern "C" void kernel_launch(void* const* d_in, const int* in_sizes, int n_in,
                              void* d_out, int out_size, void* d_ws, size_t ws_size,
                              hipStream_t stream)
{
  const float* Rg    = (const float*)d_in[0];
  const float* Tg    = (const float*)d_in[1];
  const float* rho0g = (const float*)d_in[2];
  const float* betag = (const float*)d_in[3];
  float* outg = (float*)d_out;
  sir_meta_kernel<<<NS, BLK, 0, stream>>>(Rg, Tg, rho0g, betag, outg);
}